// Round 4
// baseline (341.290 us; speedup 1.0000x reference)
//
#include <hip/hip_runtime.h>
#include <math.h>

#define NPIX 4096

// ---------------------------------------------------------------------------
// DPP-based 64-lane inclusive scan (VALU only, no LDS traffic)
// ---------------------------------------------------------------------------
template <int CTRL, int RM>
__device__ __forceinline__ float dpp_add(float x) {
    int xi = __builtin_bit_cast(int, x);
    int sh = __builtin_amdgcn_update_dpp(0, xi, CTRL, RM, 0xf, false);
    return x + __builtin_bit_cast(float, sh);
}

__device__ __forceinline__ float wave_iscan(float x) {
    x = dpp_add<0x111, 0xf>(x);   // row_shr:1
    x = dpp_add<0x112, 0xf>(x);   // row_shr:2
    x = dpp_add<0x114, 0xf>(x);   // row_shr:4
    x = dpp_add<0x118, 0xf>(x);   // row_shr:8
    x = dpp_add<0x142, 0xa>(x);   // row_bcast:15 -> rows 1,3
    x = dpp_add<0x143, 0xc>(x);   // row_bcast:31 -> rows 2,3
    return x;
}

// ---------------------------------------------------------------------------
// Kernel 1: fused QKV 1x1-conv GEMM (unchanged from R3).
// ---------------------------------------------------------------------------
__global__ __launch_bounds__(256) void qkv_kernel(
    const float* __restrict__ x, const float* __restrict__ Wq,
    const float* __restrict__ Wk, const float* __restrict__ Wv,
    float* __restrict__ qo, float* __restrict__ ko, float* __restrict__ vo)
{
    const int pt = blockIdx.x * 128;
    const int ot = blockIdx.y * 32;
    const int mat = blockIdx.z;
    const float* __restrict__ W = (mat == 0) ? Wq : ((mat == 1) ? Wk : Wv);
    float* __restrict__ out = (mat == 0) ? qo : ((mat == 1) ? ko : vo);

    __shared__ float Xs[32][132];
    __shared__ __align__(16) float Wt[32][36];   // [c][o]

    const int t = threadIdx.x;
    const int pc = t & 31;
    const int oc = t >> 5;

    float acc[4][4];
#pragma unroll
    for (int j = 0; j < 4; j++)
#pragma unroll
        for (int i = 0; i < 4; i++) acc[j][i] = 0.f;

    for (int kt = 0; kt < 256; kt += 32) {
#pragma unroll
        for (int i = 0; i < 4; i++) {
            int idx = t + (i << 8);
            int c = idx >> 5;
            int p4 = (idx & 31) << 2;
            float4 val = *reinterpret_cast<const float4*>(x + (kt + c) * NPIX + pt + p4);
            *reinterpret_cast<float4*>(&Xs[c][p4]) = val;
        }
#pragma unroll
        for (int i = 0; i < 4; i++) {
            int idx = t + (i << 8);
            int o = idx & 31;
            int c = idx >> 5;
            Wt[c][o] = W[(ot + o) * 256 + kt + c];
        }
        __syncthreads();
#pragma unroll
        for (int kk = 0; kk < 32; kk++) {
            float4 a = *reinterpret_cast<const float4*>(&Xs[kk][pc << 2]);
            float av[4] = {a.x, a.y, a.z, a.w};
            float4 b4 = *reinterpret_cast<const float4*>(&Wt[kk][oc << 2]);
            float bv[4] = {b4.x, b4.y, b4.z, b4.w};
#pragma unroll
            for (int j = 0; j < 4; j++)
#pragma unroll
                for (int i = 0; i < 4; i++)
                    acc[j][i] = fmaf(bv[j], av[i], acc[j][i]);
        }
        __syncthreads();
    }

    if (mat < 2) {
#pragma unroll
        for (int j = 0; j < 4; j++) {
            const int o = ot + (oc << 2) + j;
            float4 r;
            r.x = 1.f / (1.f + __expf(-acc[j][0]));
            r.y = 1.f / (1.f + __expf(-acc[j][1]));
            r.z = 1.f / (1.f + __expf(-acc[j][2]));
            r.w = 1.f / (1.f + __expf(-acc[j][3]));
            *reinterpret_cast<float4*>(out + o * NPIX + pt + (pc << 2)) = r;
        }
    } else {
        float* scratch = &Xs[0][0];
        __syncthreads();
#pragma unroll
        for (int i = 0; i < 4; i++) {
            float ss = 0.f;
#pragma unroll
            for (int j = 0; j < 4; j++) ss += acc[j][i] * acc[j][i];
            scratch[oc * 128 + (pc << 2) + i] = ss;
        }
        __syncthreads();
        float scale[4];
#pragma unroll
        for (int i = 0; i < 4; i++) {
            float tot = 0.f;
#pragma unroll
            for (int g = 0; g < 8; g++) tot += scratch[g * 128 + (pc << 2) + i];
            scale[i] = 1.f / fmaxf(sqrtf(tot), 1e-12f);
        }
#pragma unroll
        for (int j = 0; j < 4; j++) {
            const int o = ot + (oc << 2) + j;
            float4 r;
            r.x = acc[j][0] * scale[0];
            r.y = acc[j][1] * scale[1];
            r.z = acc[j][2] * scale[2];
            r.w = acc[j][3] * scale[3];
            *reinterpret_cast<float4*>(out + o * NPIX + pt + (pc << 2)) = r;
        }
    }
}

// ---------------------------------------------------------------------------
// Kernel 2: fused integral-image + windowed contraction, register column scan.
// Per d: (a) wave wv DPP-row-scans rows 16wv..16wv+15, keeps exclusive column
// prefix in registers; (b) per-wave column totals exchanged via csum[4][68]
// (conflict-free); (c) final P rows written as aligned float4 quads into the
// transposed tile Pt[x][yp] (yp = 32 + y; yp<32 zeros persistent; yp 97..127
// bottom-replicate pad by wave 3). 2 barriers/d, no 8-way conflicted writes.
// ONE-ARG launch_bounds (R2's (256,4) caused VGPR=64 spill catastrophe).
// ---------------------------------------------------------------------------
template <int PD>
__global__ __launch_bounds__(256) void attn_kernel(
    const float* __restrict__ q, const float* __restrict__ k,
    const float* __restrict__ v, float* __restrict__ num, float* __restrict__ nrm)
{
    const int f = blockIdx.x;          // 0..32 (32 == norm slot)
    const int head = blockIdx.y;       // 0..7
    const int dg = blockIdx.z;         // 0..(32/PD - 1)
    const bool isnorm = (f == 32);

    const float* __restrict__ kh = k + (head * 32 + dg * PD) * NPIX;
    const float* __restrict__ qh = q + (head * 32 + dg * PD) * NPIX;
    const float* __restrict__ vf = v + (head * 32 + (isnorm ? 0 : f)) * NPIX;

    __shared__ __align__(16) float Pt[65][132];   // 34,320 B
    __shared__ float csum[4][68];                 // per-wave column totals

    const int t = threadIdx.x;
    const int lane = t & 63;
    const int wv = t >> 6;

    // zero-init once; yp 0..31 (y<0) and Pt[0][*] (x=0) stay zero forever
    for (int i = t; i < 65 * 132; i += 256) (&Pt[0][0])[i] = 0.f;

    float acc[3][16];
#pragma unroll
    for (int w = 0; w < 3; w++)
#pragma unroll
        for (int i = 0; i < 16; i++) acc[w][i] = 0.f;

    for (int dd = 0; dd < PD; dd++) {
        const float* __restrict__ kd = kh + dd * NPIX;
        // (a) row scans + in-register exclusive column prefix
        float pv[16];
        float runex = 0.f;
#pragma unroll
        for (int i = 0; i < 16; i++) {
            const int r = wv * 16 + i;
            const float vv = isnorm ? 1.f : vf[r * 64 + lane];
            float rs = wave_iscan(kd[r * 64 + lane] * vv);
            pv[i] = runex;            // exclusive prefix: P[16wv+i] partial
            runex += rs;
        }
        csum[wv][lane] = runex;
        __syncthreads();              // barrier 1: csum ready (also fences
                                      // phase-4 of prev d before P rewrite)
        float off = 0.f;
        if (wv > 0) off += csum[0][lane];
        if (wv > 1) off += csum[1][lane];
        if (wv > 2) off += csum[2][lane];
#pragma unroll
        for (int i = 0; i < 16; i++) pv[i] += off;
        // (c) aligned float4 stores: column x=lane+1, yp = 32+16wv+4s
#pragma unroll
        for (int s = 0; s < 4; s++) {
            float4 r4 = make_float4(pv[4 * s], pv[4 * s + 1], pv[4 * s + 2], pv[4 * s + 3]);
            *reinterpret_cast<float4*>(&Pt[lane + 1][32 + wv * 16 + 4 * s]) = r4;
        }
        if (wv == 3) {                // bottom row y=64 + replicate pad
            const float y64 = off + runex;
            const float4 p4 = make_float4(y64, y64, y64, y64);
#pragma unroll
            for (int s = 0; s < 8; s++)
                *reinterpret_cast<float4*>(&Pt[lane + 1][96 + 4 * s]) = p4;
        }
        __syncthreads();              // barrier 2: P complete
        // phase 4: windowed box-diff contraction, float4 corner reads
        const float* __restrict__ qd = qh + dd * NPIX;
#pragma unroll
        for (int i = 0; i < 4; i++) {
            const int y0 = i * 16 + wv * 4;
            float qv[4];
#pragma unroll
            for (int j = 0; j < 4; j++) qv[j] = qd[(y0 + j) * 64 + lane];
#pragma unroll
            for (int w = 0; w < 3; w++) {
                const int hw = 32 >> w;
                const int xlo = max(lane - hw, 0);
                const int xhi = min(lane + hw, 64);
                const int ylo = 32 + y0 - hw;
                const int yhi = 32 + y0 + hw;
                float4 A4 = *reinterpret_cast<const float4*>(&Pt[xhi][yhi]);
                float4 B4 = *reinterpret_cast<const float4*>(&Pt[xlo][yhi]);
                float4 C4, E4;
                if (y0 + 3 <= hw) {   // wave-uniform: whole quad in zero pad
                    C4 = make_float4(0.f, 0.f, 0.f, 0.f);
                    E4 = C4;
                } else {
                    C4 = *reinterpret_cast<const float4*>(&Pt[xhi][ylo]);
                    E4 = *reinterpret_cast<const float4*>(&Pt[xlo][ylo]);
                }
                acc[w][i * 4 + 0] = fmaf(qv[0], (A4.x - B4.x) - (C4.x - E4.x), acc[w][i * 4 + 0]);
                acc[w][i * 4 + 1] = fmaf(qv[1], (A4.y - B4.y) - (C4.y - E4.y), acc[w][i * 4 + 1]);
                acc[w][i * 4 + 2] = fmaf(qv[2], (A4.z - B4.z) - (C4.z - E4.z), acc[w][i * 4 + 2]);
                acc[w][i * 4 + 3] = fmaf(qv[3], (A4.w - B4.w) - (C4.w - E4.w), acc[w][i * 4 + 3]);
            }
        }
        // no end barrier: next iter's csum write targets a separate tile and
        // barrier 1 fences it against this iter's phase-4 reads of Pt
    }

    float* __restrict__ nout = num + (size_t)dg * 3145728;
    float* __restrict__ rout = nrm + (size_t)dg * 98304;
#pragma unroll
    for (int w = 0; w < 3; w++) {
#pragma unroll
        for (int i = 0; i < 4; i++) {
#pragma unroll
            for (int j = 0; j < 4; j++) {
                const int px = (i * 16 + wv * 4 + j) * 64 + lane;
                const float val = acc[w][i * 4 + j];
                if (isnorm) rout[(w * 8 + head) * NPIX + px] = val;
                else        nout[((w * 8 + head) * 32 + f) * NPIX + px] = val;
            }
        }
    }
}

// ---------------------------------------------------------------------------
// Kernel 3: merge d-group partials: A = (sum_s num_s) / (sum_s nrm_s + 1e-6).
// ---------------------------------------------------------------------------
template <int NS>
__global__ __launch_bounds__(256) void merge_kernel(
    const float* __restrict__ num, const float* __restrict__ nrm,
    float* __restrict__ A)
{
    const int wh = blockIdx.y;
    const int p4 = (blockIdx.x * 256 + threadIdx.x) * 4;
    float nx = 0.f, ny = 0.f, nz = 0.f, nw = 0.f;
#pragma unroll
    for (int s = 0; s < NS; s++) {
        float4 nv = *reinterpret_cast<const float4*>(nrm + s * 98304 + wh * NPIX + p4);
        nx += nv.x; ny += nv.y; nz += nv.z; nw += nv.w;
    }
    const float rx = 1.f / (nx + 1e-6f), ry = 1.f / (ny + 1e-6f);
    const float rz = 1.f / (nz + 1e-6f), rw = 1.f / (nw + 1e-6f);
    for (int ff = 0; ff < 32; ff++) {
        float ax = 0.f, ay = 0.f, az = 0.f, aw = 0.f;
#pragma unroll
        for (int s = 0; s < NS; s++) {
            float4 tv = *reinterpret_cast<const float4*>(
                num + (size_t)s * 3145728 + (wh * 32 + ff) * NPIX + p4);
            ax += tv.x; ay += tv.y; az += tv.z; aw += tv.w;
        }
        float4 r = make_float4(ax * rx, ay * ry, az * rz, aw * rw);
        *reinterpret_cast<float4*>(A + (wh * 32 + ff) * NPIX + p4) = r;
    }
}

// ---------------------------------------------------------------------------
// Kernel 4: final 1x1 conv on merged A, B-operand transposed in LDS.
// ---------------------------------------------------------------------------
__global__ __launch_bounds__(256) void out_kernel(
    const float* __restrict__ A, const float* __restrict__ Wout,
    const float* __restrict__ bout, float* __restrict__ out)
{
    const int pt = blockIdx.x * 128;
    const int ot = blockIdx.y * 32;
    __shared__ float As[32][132];
    __shared__ __align__(16) float Wt[32][36];
    const int t = threadIdx.x;
    const int pc = t & 31;
    const int oc = t >> 5;

    float acc[4][4];
#pragma unroll
    for (int j = 0; j < 4; j++)
#pragma unroll
        for (int i = 0; i < 4; i++) acc[j][i] = 0.f;

    for (int kt = 0; kt < 24; kt++) {
        const float* __restrict__ At = A + (size_t)kt * 32 * NPIX;
#pragma unroll
        for (int i = 0; i < 4; i++) {
            int idx = t + (i << 8);
            int c = idx >> 5;
            int p4 = (idx & 31) << 2;
            *reinterpret_cast<float4*>(&As[c][p4]) =
                *reinterpret_cast<const float4*>(At + c * NPIX + pt + p4);
        }
#pragma unroll
        for (int i = 0; i < 4; i++) {
            int idx = t + (i << 8);
            int o = idx & 31;
            int c = idx >> 5;
            Wt[c][o] = Wout[(ot + o) * 768 + kt * 32 + c];
        }
        __syncthreads();
#pragma unroll
        for (int kk = 0; kk < 32; kk++) {
            float4 a = *reinterpret_cast<const float4*>(&As[kk][pc << 2]);
            float av[4] = {a.x, a.y, a.z, a.w};
            float4 b4 = *reinterpret_cast<const float4*>(&Wt[kk][oc << 2]);
            float bv[4] = {b4.x, b4.y, b4.z, b4.w};
#pragma unroll
            for (int j = 0; j < 4; j++)
#pragma unroll
                for (int i = 0; i < 4; i++)
                    acc[j][i] = fmaf(bv[j], av[i], acc[j][i]);
        }
        __syncthreads();
    }

#pragma unroll
    for (int j = 0; j < 4; j++) {
        const int o = ot + (oc << 2) + j;
        const float bb = bout[o];
        float4 r;
        r.x = acc[j][0] + bb;
        r.y = acc[j][1] + bb;
        r.z = acc[j][2] + bb;
        r.w = acc[j][3] + bb;
        *reinterpret_cast<float4*>(out + o * NPIX + pt + (pc << 2)) = r;
    }
}

extern "C" void kernel_launch(void* const* d_in, const int* in_sizes, int n_in,
                              void* d_out, int out_size, void* d_ws, size_t ws_size,
                              hipStream_t stream)
{
    const float* x    = (const float*)d_in[0];
    const float* Wq   = (const float*)d_in[1];
    const float* Wk   = (const float*)d_in[2];
    const float* Wv   = (const float*)d_in[3];
    const float* Wout = (const float*)d_in[4];
    const float* bout = (const float*)d_in[5];
    float* out = (float*)d_out;

    float* ws = (float*)d_ws;
    float* q = ws;
    float* k = ws + 1048576;
    float* v = ws + 2097152;
    float* A = ws;                    // aliases q/k/v (dead after attn)
    float* num = ws + 3145728;
    const size_t fl = ws_size / 4;

    qkv_kernel<<<dim3(32, 8, 3), 256, 0, stream>>>(x, Wq, Wk, Wv, q, k, v);

    if (fl >= 16121856) {             // NS = 4
        float* nrm = num + (size_t)4 * 3145728;
        attn_kernel<8><<<dim3(33, 8, 4), 256, 0, stream>>>(q, k, v, num, nrm);
        merge_kernel<4><<<dim3(4, 24), 256, 0, stream>>>(num, nrm, A);
    } else if (fl >= 9633792) {       // NS = 2
        float* nrm = num + (size_t)2 * 3145728;
        attn_kernel<16><<<dim3(33, 8, 2), 256, 0, stream>>>(q, k, v, num, nrm);
        merge_kernel<2><<<dim3(4, 24), 256, 0, stream>>>(num, nrm, A);
    } else {                          // NS = 1
        float* nrm = num + (size_t)3145728;
        attn_kernel<32><<<dim3(33, 8, 1), 256, 0, stream>>>(q, k, v, num, nrm);
        merge_kernel<1><<<dim3(4, 24), 256, 0, stream>>>(num, nrm, A);
    }

    out_kernel<<<dim3(32, 8), 256, 0, stream>>>(A, Wout, bout, out);
}

// Round 5
// 179.336 us; speedup vs baseline: 1.9031x; 1.9031x over previous
//
#include <hip/hip_runtime.h>
#include <math.h>

#define NPIX 4096

// ---------------------------------------------------------------------------
// DPP-based 64-lane inclusive scan (VALU only, no LDS traffic)
// ---------------------------------------------------------------------------
template <int CTRL, int RM>
__device__ __forceinline__ float dpp_add(float x) {
    int xi = __builtin_bit_cast(int, x);
    int sh = __builtin_amdgcn_update_dpp(0, xi, CTRL, RM, 0xf, false);
    return x + __builtin_bit_cast(float, sh);
}

__device__ __forceinline__ float wave_iscan(float x) {
    x = dpp_add<0x111, 0xf>(x);   // row_shr:1
    x = dpp_add<0x112, 0xf>(x);   // row_shr:2
    x = dpp_add<0x114, 0xf>(x);   // row_shr:4
    x = dpp_add<0x118, 0xf>(x);   // row_shr:8
    x = dpp_add<0x142, 0xa>(x);   // row_bcast:15 -> rows 1,3
    x = dpp_add<0x143, 0xc>(x);   // row_bcast:31 -> rows 2,3
    return x;
}

// LDS-only barrier: drain lgkm (ds ops) but leave global loads in flight.
// __syncthreads() would emit s_waitcnt vmcnt(0) and kill register prefetch.
__device__ __forceinline__ void lds_barrier() {
    asm volatile("s_waitcnt lgkmcnt(0)" ::: "memory");
    __builtin_amdgcn_s_barrier();
    __builtin_amdgcn_sched_barrier(0);
}

// ---------------------------------------------------------------------------
// Kernel 1: fused QKV 1x1-conv GEMM (unchanged from R3).
// ---------------------------------------------------------------------------
__global__ __launch_bounds__(256) void qkv_kernel(
    const float* __restrict__ x, const float* __restrict__ Wq,
    const float* __restrict__ Wk, const float* __restrict__ Wv,
    float* __restrict__ qo, float* __restrict__ ko, float* __restrict__ vo)
{
    const int pt = blockIdx.x * 128;
    const int ot = blockIdx.y * 32;
    const int mat = blockIdx.z;
    const float* __restrict__ W = (mat == 0) ? Wq : ((mat == 1) ? Wk : Wv);
    float* __restrict__ out = (mat == 0) ? qo : ((mat == 1) ? ko : vo);

    __shared__ float Xs[32][132];
    __shared__ __align__(16) float Wt[32][36];   // [c][o]

    const int t = threadIdx.x;
    const int pc = t & 31;
    const int oc = t >> 5;

    float acc[4][4];
#pragma unroll
    for (int j = 0; j < 4; j++)
#pragma unroll
        for (int i = 0; i < 4; i++) acc[j][i] = 0.f;

    for (int kt = 0; kt < 256; kt += 32) {
#pragma unroll
        for (int i = 0; i < 4; i++) {
            int idx = t + (i << 8);
            int c = idx >> 5;
            int p4 = (idx & 31) << 2;
            float4 val = *reinterpret_cast<const float4*>(x + (kt + c) * NPIX + pt + p4);
            *reinterpret_cast<float4*>(&Xs[c][p4]) = val;
        }
#pragma unroll
        for (int i = 0; i < 4; i++) {
            int idx = t + (i << 8);
            int o = idx & 31;
            int c = idx >> 5;
            Wt[c][o] = W[(ot + o) * 256 + kt + c];
        }
        __syncthreads();
#pragma unroll
        for (int kk = 0; kk < 32; kk++) {
            float4 a = *reinterpret_cast<const float4*>(&Xs[kk][pc << 2]);
            float av[4] = {a.x, a.y, a.z, a.w};
            float4 b4 = *reinterpret_cast<const float4*>(&Wt[kk][oc << 2]);
            float bv[4] = {b4.x, b4.y, b4.z, b4.w};
#pragma unroll
            for (int j = 0; j < 4; j++)
#pragma unroll
                for (int i = 0; i < 4; i++)
                    acc[j][i] = fmaf(bv[j], av[i], acc[j][i]);
        }
        __syncthreads();
    }

    if (mat < 2) {
#pragma unroll
        for (int j = 0; j < 4; j++) {
            const int o = ot + (oc << 2) + j;
            float4 r;
            r.x = 1.f / (1.f + __expf(-acc[j][0]));
            r.y = 1.f / (1.f + __expf(-acc[j][1]));
            r.z = 1.f / (1.f + __expf(-acc[j][2]));
            r.w = 1.f / (1.f + __expf(-acc[j][3]));
            *reinterpret_cast<float4*>(out + o * NPIX + pt + (pc << 2)) = r;
        }
    } else {
        float* scratch = &Xs[0][0];
        __syncthreads();
#pragma unroll
        for (int i = 0; i < 4; i++) {
            float ss = 0.f;
#pragma unroll
            for (int j = 0; j < 4; j++) ss += acc[j][i] * acc[j][i];
            scratch[oc * 128 + (pc << 2) + i] = ss;
        }
        __syncthreads();
        float scale[4];
#pragma unroll
        for (int i = 0; i < 4; i++) {
            float tot = 0.f;
#pragma unroll
            for (int g = 0; g < 8; g++) tot += scratch[g * 128 + (pc << 2) + i];
            scale[i] = 1.f / fmaxf(sqrtf(tot), 1e-12f);
        }
#pragma unroll
        for (int j = 0; j < 4; j++) {
            const int o = ot + (oc << 2) + j;
            float4 r;
            r.x = acc[j][0] * scale[0];
            r.y = acc[j][1] * scale[1];
            r.z = acc[j][2] * scale[2];
            r.w = acc[j][3] * scale[3];
            *reinterpret_cast<float4*>(out + o * NPIX + pt + (pc << 2)) = r;
        }
    }
}

// ---------------------------------------------------------------------------
// Kernel 2: fused integral-image + windowed contraction, 512 threads (8 waves).
// R3 phase structure (known-good), with:
//  - per-thread state halved (8 rows/cols/px per thread) to stay <=128 VGPR
//    (R4 lesson: 136 VGPR halves residency; R2 lesson: forced 64 spills)
//  - register prefetch: q (this d) and k (next d) issued before phase 1
//  - lds_barrier (lgkmcnt-only) so prefetched loads survive barriers
// Transposed tile Pt[x][yp], yp = 32+y: yp 0..32 zeros persistent, 33..96
// data, 97..127 bottom-replicate pad, Pt[0][*] = 0 persistent.
// ---------------------------------------------------------------------------
template <int PD>
__global__ __launch_bounds__(512) void attn_kernel(
    const float* __restrict__ q, const float* __restrict__ k,
    const float* __restrict__ v, float* __restrict__ num, float* __restrict__ nrm)
{
    const int f = blockIdx.x;          // 0..32 (32 == norm slot)
    const int head = blockIdx.y;       // 0..7
    const int dg = blockIdx.z;         // 0..(32/PD - 1)
    const bool isnorm = (f == 32);

    const float* __restrict__ kh = k + (head * 32 + dg * PD) * NPIX;
    const float* __restrict__ qh = q + (head * 32 + dg * PD) * NPIX;
    const float* __restrict__ vf = v + (head * 32 + (isnorm ? 0 : f)) * NPIX;

    __shared__ __align__(16) float Pt[65][132];   // 34,320 B

    const int t = threadIdx.x;
    const int lane = t & 63;
    const int wv = t >> 6;             // 0..7

    for (int i = t; i < 65 * 132; i += 512) (&Pt[0][0])[i] = 0.f;

    float vreg[8], kcur[8];
#pragma unroll
    for (int i = 0; i < 8; i++) {
        const int r = wv * 8 + i;
        vreg[i] = isnorm ? 1.f : vf[r * 64 + lane];
        kcur[i] = kh[r * 64 + lane];
    }

    float acc[3][8];
#pragma unroll
    for (int w = 0; w < 3; w++)
#pragma unroll
        for (int i = 0; i < 8; i++) acc[w][i] = 0.f;

    lds_barrier();                     // zero-init visible

    for (int dd = 0; dd < PD; dd++) {
        // --- prefetch: q for THIS d (used in phase 4), k for NEXT d ---
        float qv[8];
#pragma unroll
        for (int g = 0; g < 2; g++)
#pragma unroll
            for (int j = 0; j < 4; j++)
                qv[g * 4 + j] = qh[dd * NPIX + ((wv + 8 * g) * 4 + j) * 64 + lane];
        float knxt[8];
        if (dd + 1 < PD) {
#pragma unroll
            for (int i = 0; i < 8; i++)
                knxt[i] = kh[(dd + 1) * NPIX + (wv * 8 + i) * 64 + lane];
        }
        // --- phase 1: row scans (wave owns rows wv*8..wv*8+7), transposed store
#pragma unroll
        for (int i = 0; i < 8; i++) {
            float run = wave_iscan(kcur[i] * vreg[i]);
            Pt[lane + 1][33 + wv * 8 + i] = run;
        }
        lds_barrier();
        // --- phase 2: column scans (8 cols per wave) + bottom replicate pad
#pragma unroll
        for (int cc = 0; cc < 8; cc++) {
            const int xs = 1 + wv * 8 + cc;
            float run = Pt[xs][33 + lane];
            run = wave_iscan(run);
            Pt[xs][33 + lane] = run;
            float tot = __builtin_bit_cast(float,
                __builtin_amdgcn_readlane(__builtin_bit_cast(int, run), 63));
            if (lane < 31) Pt[xs][97 + lane] = tot;
        }
        lds_barrier();
        // --- phase 4: windowed box-diff contraction, float4 corner reads
#pragma unroll
        for (int g = 0; g < 2; g++) {
            const int y0 = (wv + 8 * g) * 4;
#pragma unroll
            for (int w = 0; w < 3; w++) {
                const int hw = 32 >> w;
                const int xlo = max(lane - hw, 0);
                const int xhi = min(lane + hw, 64);
                const int ylo = 32 + y0 - hw;
                const int yhi = 32 + y0 + hw;
                float4 A4 = *reinterpret_cast<const float4*>(&Pt[xhi][yhi]);
                float4 B4 = *reinterpret_cast<const float4*>(&Pt[xlo][yhi]);
                float4 C4, E4;
                if (y0 + 3 <= hw) {    // wave-uniform: whole quad in zero pad
                    C4 = make_float4(0.f, 0.f, 0.f, 0.f);
                    E4 = C4;
                } else {
                    C4 = *reinterpret_cast<const float4*>(&Pt[xhi][ylo]);
                    E4 = *reinterpret_cast<const float4*>(&Pt[xlo][ylo]);
                }
                acc[w][g * 4 + 0] = fmaf(qv[g * 4 + 0], (A4.x - B4.x) - (C4.x - E4.x), acc[w][g * 4 + 0]);
                acc[w][g * 4 + 1] = fmaf(qv[g * 4 + 1], (A4.y - B4.y) - (C4.y - E4.y), acc[w][g * 4 + 1]);
                acc[w][g * 4 + 2] = fmaf(qv[g * 4 + 2], (A4.z - B4.z) - (C4.z - E4.z), acc[w][g * 4 + 2]);
                acc[w][g * 4 + 3] = fmaf(qv[g * 4 + 3], (A4.w - B4.w) - (C4.w - E4.w), acc[w][g * 4 + 3]);
            }
        }
        lds_barrier();                 // protect Pt before next iter's rewrite
        if (dd + 1 < PD) {
#pragma unroll
            for (int i = 0; i < 8; i++) kcur[i] = knxt[i];
        }
    }

    float* __restrict__ nout = num + (size_t)dg * 3145728;
    float* __restrict__ rout = nrm + (size_t)dg * 98304;
#pragma unroll
    for (int w = 0; w < 3; w++) {
#pragma unroll
        for (int g = 0; g < 2; g++) {
#pragma unroll
            for (int j = 0; j < 4; j++) {
                const int px = ((wv + 8 * g) * 4 + j) * 64 + lane;
                const float val = acc[w][g * 4 + j];
                if (isnorm) rout[(w * 8 + head) * NPIX + px] = val;
                else        nout[((w * 8 + head) * 32 + f) * NPIX + px] = val;
            }
        }
    }
}

// ---------------------------------------------------------------------------
// Kernel 3: merge d-group partials: A = (sum_s num_s) / (sum_s nrm_s + 1e-6).
// ---------------------------------------------------------------------------
template <int NS>
__global__ __launch_bounds__(256) void merge_kernel(
    const float* __restrict__ num, const float* __restrict__ nrm,
    float* __restrict__ A)
{
    const int wh = blockIdx.y;
    const int p4 = (blockIdx.x * 256 + threadIdx.x) * 4;
    float nx = 0.f, ny = 0.f, nz = 0.f, nw = 0.f;
#pragma unroll
    for (int s = 0; s < NS; s++) {
        float4 nv = *reinterpret_cast<const float4*>(nrm + s * 98304 + wh * NPIX + p4);
        nx += nv.x; ny += nv.y; nz += nv.z; nw += nv.w;
    }
    const float rx = 1.f / (nx + 1e-6f), ry = 1.f / (ny + 1e-6f);
    const float rz = 1.f / (nz + 1e-6f), rw = 1.f / (nw + 1e-6f);
    for (int ff = 0; ff < 32; ff++) {
        float ax = 0.f, ay = 0.f, az = 0.f, aw = 0.f;
#pragma unroll
        for (int s = 0; s < NS; s++) {
            float4 tv = *reinterpret_cast<const float4*>(
                num + (size_t)s * 3145728 + (wh * 32 + ff) * NPIX + p4);
            ax += tv.x; ay += tv.y; az += tv.z; aw += tv.w;
        }
        float4 r = make_float4(ax * rx, ay * ry, az * rz, aw * rw);
        *reinterpret_cast<float4*>(A + (wh * 32 + ff) * NPIX + p4) = r;
    }
}

// ---------------------------------------------------------------------------
// Kernel 4: final 1x1 conv on merged A, B-operand transposed in LDS.
// ---------------------------------------------------------------------------
__global__ __launch_bounds__(256) void out_kernel(
    const float* __restrict__ A, const float* __restrict__ Wout,
    const float* __restrict__ bout, float* __restrict__ out)
{
    const int pt = blockIdx.x * 128;
    const int ot = blockIdx.y * 32;
    __shared__ float As[32][132];
    __shared__ __align__(16) float Wt[32][36];
    const int t = threadIdx.x;
    const int pc = t & 31;
    const int oc = t >> 5;

    float acc[4][4];
#pragma unroll
    for (int j = 0; j < 4; j++)
#pragma unroll
        for (int i = 0; i < 4; i++) acc[j][i] = 0.f;

    for (int kt = 0; kt < 24; kt++) {
        const float* __restrict__ At = A + (size_t)kt * 32 * NPIX;
#pragma unroll
        for (int i = 0; i < 4; i++) {
            int idx = t + (i << 8);
            int c = idx >> 5;
            int p4 = (idx & 31) << 2;
            *reinterpret_cast<float4*>(&As[c][p4]) =
                *reinterpret_cast<const float4*>(At + c * NPIX + pt + p4);
        }
#pragma unroll
        for (int i = 0; i < 4; i++) {
            int idx = t + (i << 8);
            int o = idx & 31;
            int c = idx >> 5;
            Wt[c][o] = Wout[(ot + o) * 768 + kt * 32 + c];
        }
        __syncthreads();
#pragma unroll
        for (int kk = 0; kk < 32; kk++) {
            float4 a = *reinterpret_cast<const float4*>(&As[kk][pc << 2]);
            float av[4] = {a.x, a.y, a.z, a.w};
            float4 b4 = *reinterpret_cast<const float4*>(&Wt[kk][oc << 2]);
            float bv[4] = {b4.x, b4.y, b4.z, b4.w};
#pragma unroll
            for (int j = 0; j < 4; j++)
#pragma unroll
                for (int i = 0; i < 4; i++)
                    acc[j][i] = fmaf(bv[j], av[i], acc[j][i]);
        }
        __syncthreads();
    }

#pragma unroll
    for (int j = 0; j < 4; j++) {
        const int o = ot + (oc << 2) + j;
        const float bb = bout[o];
        float4 r;
        r.x = acc[j][0] + bb;
        r.y = acc[j][1] + bb;
        r.z = acc[j][2] + bb;
        r.w = acc[j][3] + bb;
        *reinterpret_cast<float4*>(out + o * NPIX + pt + (pc << 2)) = r;
    }
}

extern "C" void kernel_launch(void* const* d_in, const int* in_sizes, int n_in,
                              void* d_out, int out_size, void* d_ws, size_t ws_size,
                              hipStream_t stream)
{
    const float* x    = (const float*)d_in[0];
    const float* Wq   = (const float*)d_in[1];
    const float* Wk   = (const float*)d_in[2];
    const float* Wv   = (const float*)d_in[3];
    const float* Wout = (const float*)d_in[4];
    const float* bout = (const float*)d_in[5];
    float* out = (float*)d_out;

    float* ws = (float*)d_ws;
    float* q = ws;
    float* k = ws + 1048576;
    float* v = ws + 2097152;
    float* A = ws;                    // aliases q/k/v (dead after attn)
    float* num = ws + 3145728;
    const size_t fl = ws_size / 4;

    qkv_kernel<<<dim3(32, 8, 3), 256, 0, stream>>>(x, Wq, Wk, Wv, q, k, v);

    if (fl >= 16121856) {             // NS = 4
        float* nrm = num + (size_t)4 * 3145728;
        attn_kernel<8><<<dim3(33, 8, 4), 512, 0, stream>>>(q, k, v, num, nrm);
        merge_kernel<4><<<dim3(4, 24), 256, 0, stream>>>(num, nrm, A);
    } else if (fl >= 9633792) {       // NS = 2
        float* nrm = num + (size_t)2 * 3145728;
        attn_kernel<16><<<dim3(33, 8, 2), 512, 0, stream>>>(q, k, v, num, nrm);
        merge_kernel<2><<<dim3(4, 24), 256, 0, stream>>>(num, nrm, A);
    } else {                          // NS = 1
        float* nrm = num + (size_t)3145728;
        attn_kernel<32><<<dim3(33, 8, 1), 512, 0, stream>>>(q, k, v, num, nrm);
        merge_kernel<1><<<dim3(4, 24), 256, 0, stream>>>(num, nrm, A);
    }

    out_kernel<<<dim3(32, 8), 256, 0, stream>>>(A, Wout, bout, out);
}

// Round 6
// 174.976 us; speedup vs baseline: 1.9505x; 1.0249x over previous
//
#include <hip/hip_runtime.h>
#include <math.h>

#define NPIX 4096

// ---------------------------------------------------------------------------
// DPP-based 64-lane inclusive scan (VALU only, no LDS traffic)
// ---------------------------------------------------------------------------
template <int CTRL, int RM>
__device__ __forceinline__ float dpp_add(float x) {
    int xi = __builtin_bit_cast(int, x);
    int sh = __builtin_amdgcn_update_dpp(0, xi, CTRL, RM, 0xf, false);
    return x + __builtin_bit_cast(float, sh);
}

__device__ __forceinline__ float wave_iscan(float x) {
    x = dpp_add<0x111, 0xf>(x);   // row_shr:1
    x = dpp_add<0x112, 0xf>(x);   // row_shr:2
    x = dpp_add<0x114, 0xf>(x);   // row_shr:4
    x = dpp_add<0x118, 0xf>(x);   // row_shr:8
    x = dpp_add<0x142, 0xa>(x);   // row_bcast:15 -> rows 1,3
    x = dpp_add<0x143, 0xc>(x);   // row_bcast:31 -> rows 2,3
    return x;
}

// LDS-only barrier: drain lgkm (ds ops) but leave global loads in flight.
__device__ __forceinline__ void lds_barrier() {
    asm volatile("s_waitcnt lgkmcnt(0)" ::: "memory");
    __builtin_amdgcn_s_barrier();
    __builtin_amdgcn_sched_barrier(0);
}

// ---------------------------------------------------------------------------
// Kernel 1: fused QKV 1x1-conv GEMM, 64px x 64out tiles (halved re-reads vs
// 128x32). grid (64 p-tiles, 4 o-tiles, 3 mats), 256 threads.
// ---------------------------------------------------------------------------
__global__ __launch_bounds__(256) void qkv_kernel(
    const float* __restrict__ x, const float* __restrict__ Wq,
    const float* __restrict__ Wk, const float* __restrict__ Wv,
    float* __restrict__ qo, float* __restrict__ ko, float* __restrict__ vo)
{
    const int pt = blockIdx.x * 64;
    const int ot = blockIdx.y * 64;
    const int mat = blockIdx.z;
    const float* __restrict__ W = (mat == 0) ? Wq : ((mat == 1) ? Wk : Wv);
    float* __restrict__ out = (mat == 0) ? qo : ((mat == 1) ? ko : vo);

    __shared__ __align__(16) float Xs[32][68];
    __shared__ __align__(16) float Wt[32][68];   // [c][o]

    const int t = threadIdx.x;
    const int pc = t & 15;    // 16 pixel groups x 4 px
    const int oc = t >> 4;    // 16 output groups x 4 o

    float acc[4][4];
#pragma unroll
    for (int j = 0; j < 4; j++)
#pragma unroll
        for (int i = 0; i < 4; i++) acc[j][i] = 0.f;

    for (int kt = 0; kt < 256; kt += 32) {
#pragma unroll
        for (int i = 0; i < 2; i++) {
            int idx = t + (i << 8);            // 512 float4 slots
            int c = idx >> 4;
            int p4 = (idx & 15) << 2;
            *reinterpret_cast<float4*>(&Xs[c][p4]) =
                *reinterpret_cast<const float4*>(x + (kt + c) * NPIX + pt + p4);
        }
#pragma unroll
        for (int i = 0; i < 8; i++) {
            int idx = t + (i << 8);
            int o = idx & 63;                  // lanes walk o -> conflict-free
            int c = idx >> 6;
            Wt[c][o] = W[(ot + o) * 256 + kt + c];
        }
        __syncthreads();
#pragma unroll
        for (int kk = 0; kk < 32; kk++) {
            float4 a = *reinterpret_cast<const float4*>(&Xs[kk][pc << 2]);
            float av[4] = {a.x, a.y, a.z, a.w};
            float4 b4 = *reinterpret_cast<const float4*>(&Wt[kk][oc << 2]);
            float bv[4] = {b4.x, b4.y, b4.z, b4.w};
#pragma unroll
            for (int j = 0; j < 4; j++)
#pragma unroll
                for (int i = 0; i < 4; i++)
                    acc[j][i] = fmaf(bv[j], av[i], acc[j][i]);
        }
        __syncthreads();
    }

    if (mat < 2) {
#pragma unroll
        for (int j = 0; j < 4; j++) {
            const int o = ot + (oc << 2) + j;
            float4 r;
            r.x = 1.f / (1.f + __expf(-acc[j][0]));
            r.y = 1.f / (1.f + __expf(-acc[j][1]));
            r.z = 1.f / (1.f + __expf(-acc[j][2]));
            r.w = 1.f / (1.f + __expf(-acc[j][3]));
            *reinterpret_cast<float4*>(out + o * NPIX + pt + (pc << 2)) = r;
        }
    } else {
        // v: L2-normalize per head; o-tile 64 = 2 heads (h = oc>>3)
        float* scratch = &Xs[0][0];            // 16*64 = 1024 <= 2176 floats
        __syncthreads();
#pragma unroll
        for (int i = 0; i < 4; i++) {
            float ss = 0.f;
#pragma unroll
            for (int j = 0; j < 4; j++) ss += acc[j][i] * acc[j][i];
            scratch[oc * 64 + (pc << 2) + i] = ss;
        }
        __syncthreads();
        const int hbase = (oc >> 3) << 3;      // 0 or 8
        float scale[4];
#pragma unroll
        for (int i = 0; i < 4; i++) {
            float tot = 0.f;
#pragma unroll
            for (int g = 0; g < 8; g++) tot += scratch[(hbase + g) * 64 + (pc << 2) + i];
            scale[i] = 1.f / fmaxf(sqrtf(tot), 1e-12f);
        }
#pragma unroll
        for (int j = 0; j < 4; j++) {
            const int o = ot + (oc << 2) + j;
            float4 r;
            r.x = acc[j][0] * scale[0];
            r.y = acc[j][1] * scale[1];
            r.z = acc[j][2] * scale[2];
            r.w = acc[j][3] * scale[3];
            *reinterpret_cast<float4*>(out + o * NPIX + pt + (pc << 2)) = r;
        }
    }
}

// ---------------------------------------------------------------------------
// Kernel 2: fused integral-image + windowed contraction, 512 threads (8 waves).
// R6: column scan in REGISTERS (exclusive prefix -> 16B-aligned float4 stores,
// base yp = 32+8*wv), per-wave totals via csum[8][68]. 2 barriers/d-iter:
//   iscans -> csum write -> [A] -> off + P-stores -> [B] -> phase-4 reads.
// Barrier A of iter i+1 fences iter i's phase-4 reads vs P rewrite (csum is a
// disjoint tile). Register prefetch of q (this d) and k (next d) kept from R5;
// lgkm-only barriers keep those loads in flight.
// VGPR budget: acc24+pv8+kcur8+vreg8+qv8+addr ~= 72 (target <=73 for 7 w/SIMD;
// R4 lesson: crossing 128 at 256thr halved residency; R2: forced cap spills).
// ---------------------------------------------------------------------------
template <int PD>
__global__ __launch_bounds__(512) void attn_kernel(
    const float* __restrict__ q, const float* __restrict__ k,
    const float* __restrict__ v, float* __restrict__ num, float* __restrict__ nrm)
{
    const int f = blockIdx.x;          // 0..32 (32 == norm slot)
    const int head = blockIdx.y;       // 0..7
    const int dg = blockIdx.z;         // 0..(32/PD - 1)
    const bool isnorm = (f == 32);

    const float* __restrict__ kh = k + (head * 32 + dg * PD) * NPIX;
    const float* __restrict__ qh = q + (head * 32 + dg * PD) * NPIX;
    const float* __restrict__ vf = v + (head * 32 + (isnorm ? 0 : f)) * NPIX;

    __shared__ __align__(16) float Pt[65][132];   // 34,320 B
    __shared__ float csum[8][68];                 // per-wave column totals

    const int t = threadIdx.x;
    const int lane = t & 63;
    const int wv = t >> 6;             // 0..7

    // zero-init once; yp 0..31 (y<0) and Pt[0][*] (x=0) stay zero forever
    for (int i = t; i < 65 * 132; i += 512) (&Pt[0][0])[i] = 0.f;

    float vreg[8], kcur[8];
#pragma unroll
    for (int i = 0; i < 8; i++) {
        const int r = wv * 8 + i;
        vreg[i] = isnorm ? 1.f : vf[r * 64 + lane];
        kcur[i] = kh[r * 64 + lane];
    }

    float acc[3][8];
#pragma unroll
    for (int w = 0; w < 3; w++)
#pragma unroll
        for (int i = 0; i < 8; i++) acc[w][i] = 0.f;

    lds_barrier();                     // zero-init visible

    for (int dd = 0; dd < PD; dd++) {
        // prefetch q for THIS d (consumed in phase 4)
        float qv[8];
#pragma unroll
        for (int g = 0; g < 2; g++)
#pragma unroll
            for (int j = 0; j < 4; j++)
                qv[g * 4 + j] = qh[dd * NPIX + ((wv + 8 * g) * 4 + j) * 64 + lane];

        // phase 1: row iscans + in-register EXCLUSIVE column prefix
        float pv[8];
        float run = 0.f;
#pragma unroll
        for (int i = 0; i < 8; i++) {
            float rs = wave_iscan(kcur[i] * vreg[i]);
            pv[i] = run;               // P row (8*wv + i)
            run += rs;
        }
        // kcur consumed: reload in place for next d (covered by phase 4)
        if (dd + 1 < PD) {
#pragma unroll
            for (int i = 0; i < 8; i++)
                kcur[i] = kh[(dd + 1) * NPIX + (wv * 8 + i) * 64 + lane];
        }
        csum[wv][lane] = run;
        lds_barrier();                 // A: csum ready; fences prev phase-4
        float off = 0.f;
#pragma unroll
        for (int w2 = 0; w2 < 7; w2++) if (w2 < wv) off += csum[w2][lane];
#pragma unroll
        for (int i = 0; i < 8; i++) pv[i] += off;
        // aligned float4 stores: column x=lane+1, yp = 32+8wv (==0 mod 4)
#pragma unroll
        for (int s = 0; s < 2; s++) {
            float4 r4 = make_float4(pv[4 * s], pv[4 * s + 1], pv[4 * s + 2], pv[4 * s + 3]);
            *reinterpret_cast<float4*>(&Pt[lane + 1][32 + wv * 8 + 4 * s]) = r4;
        }
        if (wv == 7) {                 // row y=64 (yp 96) + replicate pad
            const float tot = off + run;
            const float4 p4 = make_float4(tot, tot, tot, tot);
#pragma unroll
            for (int s = 0; s < 8; s++)
                *reinterpret_cast<float4*>(&Pt[lane + 1][96 + 4 * s]) = p4;
        }
        lds_barrier();                 // B: P complete
        // phase 4: windowed box-diff contraction, float4 corner reads
#pragma unroll
        for (int g = 0; g < 2; g++) {
            const int y0 = (wv + 8 * g) * 4;
#pragma unroll
            for (int w = 0; w < 3; w++) {
                const int hw = 32 >> w;
                const int xlo = max(lane - hw, 0);
                const int xhi = min(lane + hw, 64);
                const int ylo = 32 + y0 - hw;
                const int yhi = 32 + y0 + hw;
                float4 A4 = *reinterpret_cast<const float4*>(&Pt[xhi][yhi]);
                float4 B4 = *reinterpret_cast<const float4*>(&Pt[xlo][yhi]);
                float4 C4, E4;
                if (y0 + 3 <= hw) {    // wave-uniform: whole quad in zero pad
                    C4 = make_float4(0.f, 0.f, 0.f, 0.f);
                    E4 = C4;
                } else {
                    C4 = *reinterpret_cast<const float4*>(&Pt[xhi][ylo]);
                    E4 = *reinterpret_cast<const float4*>(&Pt[xlo][ylo]);
                }
                acc[w][g * 4 + 0] = fmaf(qv[g * 4 + 0], (A4.x - B4.x) - (C4.x - E4.x), acc[w][g * 4 + 0]);
                acc[w][g * 4 + 1] = fmaf(qv[g * 4 + 1], (A4.y - B4.y) - (C4.y - E4.y), acc[w][g * 4 + 1]);
                acc[w][g * 4 + 2] = fmaf(qv[g * 4 + 2], (A4.z - B4.z) - (C4.z - E4.z), acc[w][g * 4 + 2]);
                acc[w][g * 4 + 3] = fmaf(qv[g * 4 + 3], (A4.w - B4.w) - (C4.w - E4.w), acc[w][g * 4 + 3]);
            }
        }
        // no trailing barrier: next iter's barrier A fences Pt rewrite
    }

    float* __restrict__ nout = num + (size_t)dg * 3145728;
    float* __restrict__ rout = nrm + (size_t)dg * 98304;
#pragma unroll
    for (int w = 0; w < 3; w++) {
#pragma unroll
        for (int g = 0; g < 2; g++) {
#pragma unroll
            for (int j = 0; j < 4; j++) {
                const int px = ((wv + 8 * g) * 4 + j) * 64 + lane;
                const float val = acc[w][g * 4 + j];
                if (isnorm) rout[(w * 8 + head) * NPIX + px] = val;
                else        nout[((w * 8 + head) * 32 + f) * NPIX + px] = val;
            }
        }
    }
}

// ---------------------------------------------------------------------------
// Kernel 3: merge d-group partials: A = (sum_s num_s) / (sum_s nrm_s + 1e-6).
// ---------------------------------------------------------------------------
template <int NS>
__global__ __launch_bounds__(256) void merge_kernel(
    const float* __restrict__ num, const float* __restrict__ nrm,
    float* __restrict__ A)
{
    const int wh = blockIdx.y;
    const int p4 = (blockIdx.x * 256 + threadIdx.x) * 4;
    float nx = 0.f, ny = 0.f, nz = 0.f, nw = 0.f;
#pragma unroll
    for (int s = 0; s < NS; s++) {
        float4 nv = *reinterpret_cast<const float4*>(nrm + s * 98304 + wh * NPIX + p4);
        nx += nv.x; ny += nv.y; nz += nv.z; nw += nv.w;
    }
    const float rx = 1.f / (nx + 1e-6f), ry = 1.f / (ny + 1e-6f);
    const float rz = 1.f / (nz + 1e-6f), rw = 1.f / (nw + 1e-6f);
    for (int ff = 0; ff < 32; ff++) {
        float ax = 0.f, ay = 0.f, az = 0.f, aw = 0.f;
#pragma unroll
        for (int s = 0; s < NS; s++) {
            float4 tv = *reinterpret_cast<const float4*>(
                num + (size_t)s * 3145728 + (wh * 32 + ff) * NPIX + p4);
            ax += tv.x; ay += tv.y; az += tv.z; aw += tv.w;
        }
        float4 r = make_float4(ax * rx, ay * ry, az * rz, aw * rw);
        *reinterpret_cast<float4*>(A + (wh * 32 + ff) * NPIX + p4) = r;
    }
}

// ---------------------------------------------------------------------------
// Kernel 4: final 1x1 conv on merged A, 64px x 64out tiles. grid (64, 4).
// ---------------------------------------------------------------------------
__global__ __launch_bounds__(256) void out_kernel(
    const float* __restrict__ A, const float* __restrict__ Wout,
    const float* __restrict__ bout, float* __restrict__ out)
{
    const int pt = blockIdx.x * 64;
    const int ot = blockIdx.y * 64;
    __shared__ __align__(16) float As[32][68];
    __shared__ __align__(16) float Wt[32][68];
    const int t = threadIdx.x;
    const int pc = t & 15;
    const int oc = t >> 4;

    float acc[4][4];
#pragma unroll
    for (int j = 0; j < 4; j++)
#pragma unroll
        for (int i = 0; i < 4; i++) acc[j][i] = 0.f;

    for (int kt = 0; kt < 24; kt++) {
        const float* __restrict__ At = A + (size_t)kt * 32 * NPIX;
#pragma unroll
        for (int i = 0; i < 2; i++) {
            int idx = t + (i << 8);
            int c = idx >> 4;
            int p4 = (idx & 15) << 2;
            *reinterpret_cast<float4*>(&As[c][p4]) =
                *reinterpret_cast<const float4*>(At + c * NPIX + pt + p4);
        }
#pragma unroll
        for (int i = 0; i < 8; i++) {
            int idx = t + (i << 8);
            int o = idx & 63;
            int c = idx >> 6;
            Wt[c][o] = Wout[(ot + o) * 768 + kt * 32 + c];
        }
        __syncthreads();
#pragma unroll
        for (int kk = 0; kk < 32; kk++) {
            float4 a = *reinterpret_cast<const float4*>(&As[kk][pc << 2]);
            float av[4] = {a.x, a.y, a.z, a.w};
            float4 b4 = *reinterpret_cast<const float4*>(&Wt[kk][oc << 2]);
            float bv[4] = {b4.x, b4.y, b4.z, b4.w};
#pragma unroll
            for (int j = 0; j < 4; j++)
#pragma unroll
                for (int i = 0; i < 4; i++)
                    acc[j][i] = fmaf(bv[j], av[i], acc[j][i]);
        }
        __syncthreads();
    }

#pragma unroll
    for (int j = 0; j < 4; j++) {
        const int o = ot + (oc << 2) + j;
        const float bb = bout[o];
        float4 r;
        r.x = acc[j][0] + bb;
        r.y = acc[j][1] + bb;
        r.z = acc[j][2] + bb;
        r.w = acc[j][3] + bb;
        *reinterpret_cast<float4*>(out + o * NPIX + pt + (pc << 2)) = r;
    }
}

extern "C" void kernel_launch(void* const* d_in, const int* in_sizes, int n_in,
                              void* d_out, int out_size, void* d_ws, size_t ws_size,
                              hipStream_t stream)
{
    const float* x    = (const float*)d_in[0];
    const float* Wq   = (const float*)d_in[1];
    const float* Wk   = (const float*)d_in[2];
    const float* Wv   = (const float*)d_in[3];
    const float* Wout = (const float*)d_in[4];
    const float* bout = (const float*)d_in[5];
    float* out = (float*)d_out;

    float* ws = (float*)d_ws;
    float* q = ws;
    float* k = ws + 1048576;
    float* v = ws + 2097152;
    float* A = ws;                    // aliases q/k/v (dead after attn)
    float* num = ws + 3145728;
    const size_t fl = ws_size / 4;

    qkv_kernel<<<dim3(64, 4, 3), 256, 0, stream>>>(x, Wq, Wk, Wv, q, k, v);

    if (fl >= 16121856) {             // NS = 4
        float* nrm = num + (size_t)4 * 3145728;
        attn_kernel<8><<<dim3(33, 8, 4), 512, 0, stream>>>(q, k, v, num, nrm);
        merge_kernel<4><<<dim3(4, 24), 256, 0, stream>>>(num, nrm, A);
    } else if (fl >= 9633792) {       // NS = 2
        float* nrm = num + (size_t)2 * 3145728;
        attn_kernel<16><<<dim3(33, 8, 2), 512, 0, stream>>>(q, k, v, num, nrm);
        merge_kernel<2><<<dim3(4, 24), 256, 0, stream>>>(num, nrm, A);
    } else {                          // NS = 1
        float* nrm = num + (size_t)3145728;
        attn_kernel<32><<<dim3(33, 8, 1), 512, 0, stream>>>(q, k, v, num, nrm);
        merge_kernel<1><<<dim3(4, 24), 256, 0, stream>>>(num, nrm, A);
    }

    out_kernel<<<dim3(64, 4), 256, 0, stream>>>(A, Wout, bout, out);
}

// Round 7
// 162.277 us; speedup vs baseline: 2.1031x; 1.0783x over previous
//
#include <hip/hip_runtime.h>
#include <math.h>

#define NPIX 4096

// ---------------------------------------------------------------------------
// DPP-based 64-lane inclusive scan (VALU only, no LDS traffic)
// ---------------------------------------------------------------------------
template <int CTRL, int RM>
__device__ __forceinline__ float dpp_add(float x) {
    int xi = __builtin_bit_cast(int, x);
    int sh = __builtin_amdgcn_update_dpp(0, xi, CTRL, RM, 0xf, false);
    return x + __builtin_bit_cast(float, sh);
}

__device__ __forceinline__ float wave_iscan(float x) {
    x = dpp_add<0x111, 0xf>(x);   // row_shr:1
    x = dpp_add<0x112, 0xf>(x);   // row_shr:2
    x = dpp_add<0x114, 0xf>(x);   // row_shr:4
    x = dpp_add<0x118, 0xf>(x);   // row_shr:8
    x = dpp_add<0x142, 0xa>(x);   // row_bcast:15 -> rows 1,3
    x = dpp_add<0x143, 0xc>(x);   // row_bcast:31 -> rows 2,3
    return x;
}

// LDS-only barrier: drain lgkm (ds ops) but leave global loads in flight.
__device__ __forceinline__ void lds_barrier() {
    asm volatile("s_waitcnt lgkmcnt(0)" ::: "memory");
    __builtin_amdgcn_s_barrier();
    __builtin_amdgcn_sched_barrier(0);
}

// ---------------------------------------------------------------------------
// Kernel 1: fused QKV 1x1-conv GEMM, 128px x 32out tiles (R3 shape) +
// register prefetch of next K-tile (loads overlap the FMA loop; the
// __syncthreads vmcnt(0) drain before the LDS write is the wait).
// W global loads coalesced as float4 along c. grid (32, 8, 3), 256 thr.
// ---------------------------------------------------------------------------
__global__ __launch_bounds__(256) void qkv_kernel(
    const float* __restrict__ x, const float* __restrict__ Wq,
    const float* __restrict__ Wk, const float* __restrict__ Wv,
    float* __restrict__ qo, float* __restrict__ ko, float* __restrict__ vo)
{
    const int pt = blockIdx.x * 128;
    const int ot = blockIdx.y * 32;
    const int mat = blockIdx.z;
    const float* __restrict__ W = (mat == 0) ? Wq : ((mat == 1) ? Wk : Wv);
    float* __restrict__ out = (mat == 0) ? qo : ((mat == 1) ? ko : vo);

    __shared__ __align__(16) float Xs[32][132];
    __shared__ __align__(16) float Wt[32][36];   // [c][o]

    const int t = threadIdx.x;
    const int pc = t & 31;     // pixel group (4 px)
    const int oc = t >> 5;     // output group (4 o)
    const int xc = t >> 5;     // staging: base c row
    const int xp = (t & 31) << 2;
    const int lo = t >> 3;     // W loader: output row (0..31)
    const int lg = (t & 7) << 2;  // W loader: c group base

    float4 xf[4];
    float4 wf;
#pragma unroll
    for (int i = 0; i < 4; i++)
        xf[i] = *reinterpret_cast<const float4*>(x + (xc + 8 * i) * NPIX + pt + xp);
    wf = *reinterpret_cast<const float4*>(W + (ot + lo) * 256 + lg);

    float acc[4][4];
#pragma unroll
    for (int j = 0; j < 4; j++)
#pragma unroll
        for (int i = 0; i < 4; i++) acc[j][i] = 0.f;

    for (int kt = 0; kt < 256; kt += 32) {
#pragma unroll
        for (int i = 0; i < 4; i++)
            *reinterpret_cast<float4*>(&Xs[xc + 8 * i][xp]) = xf[i];
        Wt[lg + 0][lo] = wf.x;
        Wt[lg + 1][lo] = wf.y;
        Wt[lg + 2][lo] = wf.z;
        Wt[lg + 3][lo] = wf.w;
        __syncthreads();
        if (kt + 32 < 256) {   // prefetch next K-tile (in flight over FMAs)
#pragma unroll
            for (int i = 0; i < 4; i++)
                xf[i] = *reinterpret_cast<const float4*>(
                    x + (kt + 32 + xc + 8 * i) * NPIX + pt + xp);
            wf = *reinterpret_cast<const float4*>(W + (ot + lo) * 256 + kt + 32 + lg);
        }
#pragma unroll
        for (int kk = 0; kk < 32; kk++) {
            float4 a = *reinterpret_cast<const float4*>(&Xs[kk][pc << 2]);
            float av[4] = {a.x, a.y, a.z, a.w};
            float4 b4 = *reinterpret_cast<const float4*>(&Wt[kk][oc << 2]);
            float bv[4] = {b4.x, b4.y, b4.z, b4.w};
#pragma unroll
            for (int j = 0; j < 4; j++)
#pragma unroll
                for (int i = 0; i < 4; i++)
                    acc[j][i] = fmaf(bv[j], av[i], acc[j][i]);
        }
        __syncthreads();
    }

    if (mat < 2) {
#pragma unroll
        for (int j = 0; j < 4; j++) {
            const int o = ot + (oc << 2) + j;
            float4 r;
            r.x = 1.f / (1.f + __expf(-acc[j][0]));
            r.y = 1.f / (1.f + __expf(-acc[j][1]));
            r.z = 1.f / (1.f + __expf(-acc[j][2]));
            r.w = 1.f / (1.f + __expf(-acc[j][3]));
            *reinterpret_cast<float4*>(out + o * NPIX + pt + (pc << 2)) = r;
        }
    } else {
        // v: L2-normalize over the 32 channels of this head (o-tile == head)
        float* scratch = &Xs[0][0];
#pragma unroll
        for (int i = 0; i < 4; i++) {
            float ss = 0.f;
#pragma unroll
            for (int j = 0; j < 4; j++) ss += acc[j][i] * acc[j][i];
            scratch[oc * 128 + (pc << 2) + i] = ss;
        }
        __syncthreads();
        float scale[4];
#pragma unroll
        for (int i = 0; i < 4; i++) {
            float tot = 0.f;
#pragma unroll
            for (int g = 0; g < 8; g++) tot += scratch[g * 128 + (pc << 2) + i];
            scale[i] = 1.f / fmaxf(sqrtf(tot), 1e-12f);
        }
#pragma unroll
        for (int j = 0; j < 4; j++) {
            const int o = ot + (oc << 2) + j;
            float4 r;
            r.x = acc[j][0] * scale[0];
            r.y = acc[j][1] * scale[1];
            r.z = acc[j][2] * scale[2];
            r.w = acc[j][3] * scale[3];
            *reinterpret_cast<float4*>(out + o * NPIX + pt + (pc << 2)) = r;
        }
    }
}

// ---------------------------------------------------------------------------
// Kernel 2: fused integral-image + windowed contraction, 512 threads (8 waves),
// PIXEL-split (z = half of rows). Each block scans the FULL image for all 32 d
// (scan duplication is cheap: DPP in registers) but contracts only its 32
// pixel rows -> num is written final (no partials, no merge kernel).
// Norm slot (f==32) writes rnrm = 1/(x+1e-6) directly.
// Column scan in registers (R6), csum[8][68] exchange, 2 lgkm-only
// barriers/d-iter. VGPR budget ~64 (R4 lesson: stay well under cliffs).
// ---------------------------------------------------------------------------
__global__ __launch_bounds__(512) void attn_kernel(
    const float* __restrict__ q, const float* __restrict__ k,
    const float* __restrict__ v, float* __restrict__ num, float* __restrict__ rnrm)
{
    const int f = blockIdx.x;          // 0..32 (32 == norm slot)
    const int head = blockIdx.y;       // 0..7
    const int z = blockIdx.z;          // 0..1 pixel half
    const bool isnorm = (f == 32);

    const float* __restrict__ kh = k + head * 32 * NPIX;
    const float* __restrict__ qh = q + head * 32 * NPIX;
    const float* __restrict__ vf = v + (head * 32 + (isnorm ? 0 : f)) * NPIX;

    __shared__ __align__(16) float Pt[65][132];   // 34,320 B
    __shared__ float csum[8][68];

    const int t = threadIdx.x;
    const int lane = t & 63;
    const int wv = t >> 6;             // 0..7
    const int ybase = z * 32 + wv * 4; // this wave's 4 pixel rows

    for (int i = t; i < 65 * 132; i += 512) (&Pt[0][0])[i] = 0.f;

    float vreg[8], kcur[8];
#pragma unroll
    for (int i = 0; i < 8; i++) {
        const int r = wv * 8 + i;
        vreg[i] = isnorm ? 1.f : vf[r * 64 + lane];
        kcur[i] = kh[r * 64 + lane];
    }

    float acc[3][4];
#pragma unroll
    for (int w = 0; w < 3; w++)
#pragma unroll
        for (int i = 0; i < 4; i++) acc[w][i] = 0.f;

    lds_barrier();                     // zero-init visible

    for (int dd = 0; dd < 32; dd++) {
        // prefetch q for THIS d (consumed in phase 4)
        float qv[4];
#pragma unroll
        for (int j = 0; j < 4; j++)
            qv[j] = qh[dd * NPIX + (ybase + j) * 64 + lane];

        // phase 1: row iscans + in-register EXCLUSIVE column prefix
        float pv[8];
        float run = 0.f;
#pragma unroll
        for (int i = 0; i < 8; i++) {
            float rs = wave_iscan(kcur[i] * vreg[i]);
            pv[i] = run;               // P row (8*wv + i)
            run += rs;
        }
        if (dd + 1 < 32) {             // reload k for next d (covered by ph4)
#pragma unroll
            for (int i = 0; i < 8; i++)
                kcur[i] = kh[(dd + 1) * NPIX + (wv * 8 + i) * 64 + lane];
        }
        csum[wv][lane] = run;
        lds_barrier();                 // A: csum ready; fences prev phase-4
        float off = 0.f;
#pragma unroll
        for (int w2 = 0; w2 < 7; w2++) if (w2 < wv) off += csum[w2][lane];
#pragma unroll
        for (int i = 0; i < 8; i++) pv[i] += off;
#pragma unroll
        for (int s = 0; s < 2; s++) {
            float4 r4 = make_float4(pv[4 * s], pv[4 * s + 1], pv[4 * s + 2], pv[4 * s + 3]);
            *reinterpret_cast<float4*>(&Pt[lane + 1][32 + wv * 8 + 4 * s]) = r4;
        }
        if (wv == 7) {                 // row y=64 (yp 96) + replicate pad
            const float tot = off + run;
            const float4 p4 = make_float4(tot, tot, tot, tot);
#pragma unroll
            for (int s = 0; s < 8; s++)
                *reinterpret_cast<float4*>(&Pt[lane + 1][96 + 4 * s]) = p4;
        }
        lds_barrier();                 // B: P complete
        // phase 4: windowed box-diff contraction on this wave's 4 rows
#pragma unroll
        for (int w = 0; w < 3; w++) {
            const int hw = 32 >> w;
            const int xlo = max(lane - hw, 0);
            const int xhi = min(lane + hw, 64);
            const int ylo = 32 + ybase - hw;
            const int yhi = 32 + ybase + hw;
            float4 A4 = *reinterpret_cast<const float4*>(&Pt[xhi][yhi]);
            float4 B4 = *reinterpret_cast<const float4*>(&Pt[xlo][yhi]);
            float4 C4, E4;
            if (ybase + 3 <= hw) {     // wave-uniform: whole quad in zero pad
                C4 = make_float4(0.f, 0.f, 0.f, 0.f);
                E4 = C4;
            } else {
                C4 = *reinterpret_cast<const float4*>(&Pt[xhi][ylo]);
                E4 = *reinterpret_cast<const float4*>(&Pt[xlo][ylo]);
            }
            acc[w][0] = fmaf(qv[0], (A4.x - B4.x) - (C4.x - E4.x), acc[w][0]);
            acc[w][1] = fmaf(qv[1], (A4.y - B4.y) - (C4.y - E4.y), acc[w][1]);
            acc[w][2] = fmaf(qv[2], (A4.z - B4.z) - (C4.z - E4.z), acc[w][2]);
            acc[w][3] = fmaf(qv[3], (A4.w - B4.w) - (C4.w - E4.w), acc[w][3]);
        }
        // no trailing barrier: next iter's barrier A fences Pt rewrite
    }

#pragma unroll
    for (int w = 0; w < 3; w++) {
#pragma unroll
        for (int j = 0; j < 4; j++) {
            const int px = (ybase + j) * 64 + lane;
            const float val = acc[w][j];
            if (isnorm) rnrm[(w * 8 + head) * NPIX + px] = 1.f / (val + 1e-6f);
            else        num[((w * 8 + head) * 32 + f) * NPIX + px] = val;
        }
    }
}

// ---------------------------------------------------------------------------
// Kernel 3: final 1x1 conv reading num*rnrm on the fly (merge fused into
// staging; K-tile kt IS one (w,head) channel). 128px x 32out tiles +
// register prefetch. grid (32, 8), 256 threads.
// ---------------------------------------------------------------------------
__global__ __launch_bounds__(256) void out_kernel(
    const float* __restrict__ num, const float* __restrict__ rnrm,
    const float* __restrict__ Wout, const float* __restrict__ bout,
    float* __restrict__ out)
{
    const int pt = blockIdx.x * 128;
    const int ot = blockIdx.y * 32;
    __shared__ __align__(16) float As[32][132];
    __shared__ __align__(16) float Wt[32][36];
    const int t = threadIdx.x;
    const int pc = t & 31;
    const int oc = t >> 5;
    const int xc = t >> 5;
    const int xp = (t & 31) << 2;
    const int lo = t >> 3;
    const int lg = (t & 7) << 2;

    float4 nv[4], rv, wf;
#pragma unroll
    for (int i = 0; i < 4; i++)
        nv[i] = *reinterpret_cast<const float4*>(num + (size_t)(xc + 8 * i) * NPIX + pt + xp);
    rv = *reinterpret_cast<const float4*>(rnrm + pt + xp);
    wf = *reinterpret_cast<const float4*>(Wout + (ot + lo) * 768 + lg);

    float acc[4][4];
#pragma unroll
    for (int j = 0; j < 4; j++)
#pragma unroll
        for (int i = 0; i < 4; i++) acc[j][i] = 0.f;

    for (int kt = 0; kt < 24; kt++) {
#pragma unroll
        for (int i = 0; i < 4; i++) {
            float4 r;
            r.x = nv[i].x * rv.x; r.y = nv[i].y * rv.y;
            r.z = nv[i].z * rv.z; r.w = nv[i].w * rv.w;
            *reinterpret_cast<float4*>(&As[xc + 8 * i][xp]) = r;
        }
        Wt[lg + 0][lo] = wf.x;
        Wt[lg + 1][lo] = wf.y;
        Wt[lg + 2][lo] = wf.z;
        Wt[lg + 3][lo] = wf.w;
        __syncthreads();
        if (kt + 1 < 24) {             // prefetch next (w,head) channel tile
#pragma unroll
            for (int i = 0; i < 4; i++)
                nv[i] = *reinterpret_cast<const float4*>(
                    num + (size_t)((kt + 1) * 32 + xc + 8 * i) * NPIX + pt + xp);
            rv = *reinterpret_cast<const float4*>(rnrm + (kt + 1) * NPIX + pt + xp);
            wf = *reinterpret_cast<const float4*>(Wout + (ot + lo) * 768 + (kt + 1) * 32 + lg);
        }
#pragma unroll
        for (int kk = 0; kk < 32; kk++) {
            float4 a = *reinterpret_cast<const float4*>(&As[kk][pc << 2]);
            float av[4] = {a.x, a.y, a.z, a.w};
            float4 b4 = *reinterpret_cast<const float4*>(&Wt[kk][oc << 2]);
            float bv[4] = {b4.x, b4.y, b4.z, b4.w};
#pragma unroll
            for (int j = 0; j < 4; j++)
#pragma unroll
                for (int i = 0; i < 4; i++)
                    acc[j][i] = fmaf(bv[j], av[i], acc[j][i]);
        }
        __syncthreads();
    }

#pragma unroll
    for (int j = 0; j < 4; j++) {
        const int o = ot + (oc << 2) + j;
        const float bb = bout[o];
        float4 r;
        r.x = acc[j][0] + bb;
        r.y = acc[j][1] + bb;
        r.z = acc[j][2] + bb;
        r.w = acc[j][3] + bb;
        *reinterpret_cast<float4*>(out + o * NPIX + pt + (pc << 2)) = r;
    }
}

extern "C" void kernel_launch(void* const* d_in, const int* in_sizes, int n_in,
                              void* d_out, int out_size, void* d_ws, size_t ws_size,
                              hipStream_t stream)
{
    const float* x    = (const float*)d_in[0];
    const float* Wq   = (const float*)d_in[1];
    const float* Wk   = (const float*)d_in[2];
    const float* Wv   = (const float*)d_in[3];
    const float* Wout = (const float*)d_in[4];
    const float* bout = (const float*)d_in[5];
    float* out = (float*)d_out;

    float* ws = (float*)d_ws;
    float* q    = ws;                 // 1,048,576 floats
    float* k    = ws + 1048576;       // 1,048,576
    float* v    = ws + 2097152;       // 1,048,576
    float* num  = ws + 3145728;       // 3,145,728 (final, no partials)
    float* rnrm = ws + 6291456;       // 98,304 (stored as reciprocal)

    qkv_kernel<<<dim3(32, 8, 3), 256, 0, stream>>>(x, Wq, Wk, Wv, q, k, v);
    attn_kernel<<<dim3(33, 8, 2), 512, 0, stream>>>(q, k, v, num, rnrm);
    out_kernel<<<dim3(32, 8), 256, 0, stream>>>(num, rnrm, Wout, bout, out);
}